// Round 7
// baseline (114.511 us; speedup 1.0000x reference)
//
#include <hip/hip_runtime.h>

#define EPS_ 1.1920928955078125e-07f
#define SCALE_ 0.17677669529663687f   // 1/sqrt(32)

typedef __attribute__((ext_vector_type(8))) short s8b;     // 8 bf16 (16B)
typedef __attribute__((ext_vector_type(4))) float f32x4;   // MFMA acc

static __device__ __forceinline__ unsigned short f2bf(float f) {
  unsigned int u = __float_as_uint(f);
  unsigned int r = (u + 0x7fffu + ((u >> 16) & 1u)) >> 16;   // RNE
  return (unsigned short)r;
}
static __device__ __forceinline__ float b2fs(short h) {
  return __uint_as_float(((unsigned int)(unsigned short)h) << 16);
}
static __device__ __forceinline__ int S_(int c) {        // NATTEN window start (cell grid)
  return (c < 3) ? 0 : ((c > 28) ? 25 : (c - 3));
}

// ---------------------------------------------------------------------------
// prep: k-side rms+proj + weight/v packs. grid 60 x 512. (unchanged from R6)
// ---------------------------------------------------------------------------
__global__ __launch_bounds__(512) void prep_k(
    const float* __restrict__ k_in, const float* __restrict__ v_in,
    const float* __restrict__ conv_w, const float* __restrict__ normq_w,
    const float* __restrict__ normk_w, const float* __restrict__ qproj_w,
    const float* __restrict__ kproj_w, const float* __restrict__ kbias,
    unsigned short* __restrict__ vb, unsigned short* __restrict__ kpb,
    unsigned short* __restrict__ wb, unsigned short* __restrict__ wnq) {
  __shared__ __align__(16) char smem[54528];
  const int b = blockIdx.x, tid = threadIdx.x;
  const int w = tid >> 6, lane = tid & 63;
  const int lm = lane & 15, kg = lane >> 4;
  const int wm = w >> 1, wn = w & 1;

  if (b < 16) {
    unsigned short* x_l = (unsigned short*)smem;            // [64][136]
    unsigned short* wnk_l = (unsigned short*)(smem + 17408);// [128][136]
    float* red_l = (float*)(smem + 52224);                  // [512]
    float* rs_l  = (float*)(smem + 54272);                  // [64]
    const int px0 = b * 64;
    for (int i = tid; i < 2048; i += 512) {   // stage k transposed bf16
      int c = i >> 4, f = i & 15;
      float4 v = *(const float4*)&k_in[c * 1024 + px0 + f * 4];
      x_l[(f * 4 + 0) * 136 + c] = f2bf(v.x);
      x_l[(f * 4 + 1) * 136 + c] = f2bf(v.y);
      x_l[(f * 4 + 2) * 136 + c] = f2bf(v.z);
      x_l[(f * 4 + 3) * 136 + c] = f2bf(v.w);
    }
    for (int i = tid; i < 16384; i += 512) {  // wnk = kproj_w * normk
      int o = i >> 7, c = i & 127;
      wnk_l[o * 136 + c] = f2bf(kproj_w[i] * normk_w[c]);
    }
    __syncthreads();
    {
      int px = tid >> 3, t8 = tid & 7;
      float ssum = 0.f;
#pragma unroll
      for (int j = 0; j < 2; j++) {
        s8b v = *(const s8b*)&x_l[px * 136 + t8 * 16 + j * 8];
#pragma unroll
        for (int e = 0; e < 8; e++) { float f = b2fs(v[e]); ssum += f * f; }
      }
      red_l[px * 8 + t8] = ssum;
    }
    __syncthreads();
    if (tid < 64) {
      float4 r0 = *(const float4*)&red_l[tid * 8];
      float4 r1 = *(const float4*)&red_l[tid * 8 + 4];
      rs_l[tid] = rsqrtf((r0.x + r0.y + r0.z + r0.w + r1.x + r1.y + r1.z + r1.w) *
                             (1.f / 128.f) + EPS_);
    }
    __syncthreads();
    f32x4 acc[2][2];
#pragma unroll
    for (int a = 0; a < 2; a++)
#pragma unroll
      for (int n = 0; n < 2; n++) acc[a][n] = (f32x4){0.f, 0.f, 0.f, 0.f};
#pragma unroll
    for (int kc = 0; kc < 4; kc++) {
      s8b a0 = *(const s8b*)&wnk_l[(wm * 32 + lm) * 136 + kc * 32 + kg * 8];
      s8b a1 = *(const s8b*)&wnk_l[(wm * 32 + 16 + lm) * 136 + kc * 32 + kg * 8];
#pragma unroll
      for (int ni = 0; ni < 2; ni++) {
        s8b bf = *(const s8b*)&x_l[((wn * 2 + ni) * 16 + lm) * 136 + kc * 32 + kg * 8];
        acc[0][ni] = __builtin_amdgcn_mfma_f32_16x16x32_bf16(a0, bf, acc[0][ni], 0, 0, 0);
        acc[1][ni] = __builtin_amdgcn_mfma_f32_16x16x32_bf16(a1, bf, acc[1][ni], 0, 0, 0);
      }
    }
    __syncthreads();
#pragma unroll
    for (int mi = 0; mi < 2; mi++)
#pragma unroll
      for (int ni = 0; ni < 2; ni++)
#pragma unroll
        for (int r = 0; r < 4; r++) {
          int px = (wn * 2 + ni) * 16 + lm, c = wm * 32 + mi * 16 + kg * 4 + r;
          x_l[px * 136 + c] = f2bf(kbias[c] + rs_l[px] * acc[mi][ni][r]);
        }
    __syncthreads();
    for (int i = tid; i < 1024; i += 512) {
      int px = i >> 4, s = i & 15;
      *(s8b*)&kpb[(px0 + px) * 128 + s * 8] = *(const s8b*)&x_l[px * 136 + s * 8];
    }
  } else if (b < 48) {
    int g = (b - 16) * 512 + tid;             // [0,16384)
    int i32 = g & 31, oc = (g >> 5) & 127, kc = g >> 12;
    const float* src = conv_w + oc * 1152 + (kc * 32 + i32) * 9;
#pragma unroll
    for (int t = 0; t < 9; t++)
      wb[t * 16384 + g] = f2bf(src[t]);
  } else if (b < 56) {
#pragma unroll
    for (int it = 0; it < 4; it++) {
      int ch8 = (b - 48) * 2048 + it * 512 + tid;   // [0,16384) chunks of 8
      const float4 v0 = *(const float4*)&v_in[ch8 * 8];
      const float4 v1 = *(const float4*)&v_in[ch8 * 8 + 4];
      s8b o;
      o[0] = (short)f2bf(v0.x); o[1] = (short)f2bf(v0.y);
      o[2] = (short)f2bf(v0.z); o[3] = (short)f2bf(v0.w);
      o[4] = (short)f2bf(v1.x); o[5] = (short)f2bf(v1.y);
      o[6] = (short)f2bf(v1.z); o[7] = (short)f2bf(v1.w);
      *(s8b*)&vb[ch8 * 8] = o;
    }
  } else {
    int base = ((b - 56) * 512 + tid) * 8;    // [0,16384)
    const float4 v0 = *(const float4*)&qproj_w[base];
    const float4 v1 = *(const float4*)&qproj_w[base + 4];
    int c = base & 127;
    s8b o;
    o[0] = (short)f2bf(v0.x * normq_w[c + 0]); o[1] = (short)f2bf(v0.y * normq_w[c + 1]);
    o[2] = (short)f2bf(v0.z * normq_w[c + 2]); o[3] = (short)f2bf(v0.w * normq_w[c + 3]);
    o[4] = (short)f2bf(v1.x * normq_w[c + 4]); o[5] = (short)f2bf(v1.y * normq_w[c + 5]);
    o[6] = (short)f2bf(v1.z * normq_w[c + 6]); o[7] = (short)f2bf(v1.w * normq_w[c + 7]);
    *(s8b*)&wnq[base] = o;
  }
}

// ---------------------------------------------------------------------------
// conv_k: conv3x3 + in-reg RMS + qproj -> qpb [16384 px][128 ch] bf16.
// Grid 256 x 512, ONLY 2 barriers. qc_l is a separate LDS region (no overlap
// with in_l -> no conv->write barrier, and removes the R6 latent race).
// LDS: in_l [10][12][136] @0 (32640B) | qc_l [64][136] @32640 (17408B)
//      | red @50048 (1024B)  total 51072B
// ---------------------------------------------------------------------------
__global__ __launch_bounds__(512, 2) void conv_k(
    const float* __restrict__ q_in, const unsigned short* __restrict__ wb,
    const unsigned short* __restrict__ wnq, const float* __restrict__ qbias,
    unsigned short* __restrict__ qpb) {
  __shared__ __align__(16) char smem[51072];
  unsigned short* in_l = (unsigned short*)smem;
  unsigned short* qc_l = (unsigned short*)(smem + 32640);
  float* red_l = (float*)(smem + 50048);     // [64][4]

  const int tid = threadIdx.x;
  const int CY = blockIdx.x >> 4, CX = blockIdx.x & 15;
  const int Y0 = CY * 8, X0 = CX * 8;
  const int w = tid >> 6, lane = tid & 63;
  const int lm = lane & 15, kg = lane >> 4;
  const int wm = w >> 1, wn = w & 1;

  // prefetch qproj operands (L2) to overlap halo staging
  s8b wq0[4], wq1[4];
#pragma unroll
  for (int kc = 0; kc < 4; kc++) {
    wq0[kc] = *(const s8b*)&wnq[(wm * 32 + lm) * 128 + kc * 32 + kg * 8];
    wq1[kc] = *(const s8b*)&wnq[(wm * 32 + 16 + lm) * 128 + kc * 32 + kg * 8];
  }
  float4 qbv[2];
  qbv[0] = *(const float4*)&qbias[wm * 32 + kg * 4];
  qbv[1] = *(const float4*)&qbias[wm * 32 + 16 + kg * 4];

  // stage conv halo [10][12(pad)][136] directly from q_in fp32
  for (int i = tid; i < 5120; i += 512) {
    int j = i & 3, r = i >> 2;
    int ch = r & 127, ry = r >> 7;
    int y = Y0 - 1 + ry;
    int col0 = X0 - 4 + 4 * j;
    float4 v = {0.f, 0.f, 0.f, 0.f};
    if ((unsigned)y < 128u && (unsigned)col0 < 125u)
      v = *(const float4*)&q_in[ch * 16384 + y * 128 + col0];
    int rxb = 4 * j - 3;
#pragma unroll
    for (int e = 0; e < 4; e++) {
      int rx = rxb + e;
      if ((unsigned)rx < 10u)
        in_l[(ry * 12 + rx) * 136 + ch] = f2bf(((const float*)&v)[e]);
    }
  }
  __syncthreads();   // (1) halo staged

  // conv implicit GEMM, A-stream double-buffered in registers
  f32x4 acc[2][2];
#pragma unroll
  for (int a = 0; a < 2; a++)
#pragma unroll
    for (int n = 0; n < 2; n++) acc[a][n] = (f32x4){0.f, 0.f, 0.f, 0.f};
  {
    s8b wa0 = *(const s8b*)&wb[(wm * 32 + lm) * 32 + kg * 8];
    s8b wa1 = *(const s8b*)&wb[(wm * 32 + 16 + lm) * 32 + kg * 8];
#pragma unroll
    for (int idx = 0; idx < 36; idx++) {
      s8b na0 = wa0, na1 = wa1;
      if (idx < 35) {
        const unsigned short* wp = wb + (idx + 1) * 4096;
        na0 = *(const s8b*)&wp[(wm * 32 + lm) * 32 + kg * 8];
        na1 = *(const s8b*)&wp[(wm * 32 + 16 + lm) * 32 + kg * 8];
      }
      const int t = idx >> 2, kc = idx & 3;
      const int dy = t / 3, dx = t - (t / 3) * 3;
#pragma unroll
      for (int ni = 0; ni < 2; ni++) {
        int nt = wn * 2 + ni;
        int qy = 2 * nt + (lm >> 3), qx = lm & 7;
        s8b bf = *(const s8b*)&in_l[((qy + dy) * 12 + qx + dx) * 136 + kc * 32 + kg * 8];
        acc[0][ni] = __builtin_amdgcn_mfma_f32_16x16x32_bf16(wa0, bf, acc[0][ni], 0, 0, 0);
        acc[1][ni] = __builtin_amdgcn_mfma_f32_16x16x32_bf16(wa1, bf, acc[1][ni], 0, 0, 0);
      }
      wa0 = na0; wa1 = na1;
    }
  }
  // epilogue: write conv bf16 to qc_l (separate region) + rms partials
  {
    float ss[2] = {0.f, 0.f};
#pragma unroll
    for (int mi = 0; mi < 2; mi++)
#pragma unroll
      for (int ni = 0; ni < 2; ni++)
#pragma unroll
        for (int r = 0; r < 4; r++) {
          float v = acc[mi][ni][r];
          ss[ni] += v * v;
          int px = (wn * 2 + ni) * 16 + lm, c = wm * 32 + mi * 16 + kg * 4 + r;
          qc_l[px * 136 + c] = f2bf(v);
        }
#pragma unroll
    for (int ni = 0; ni < 2; ni++) {
      ss[ni] += __shfl_xor(ss[ni], 16, 64);
      ss[ni] += __shfl_xor(ss[ni], 32, 64);
    }
    if (kg == 0) {
      red_l[((wn * 2 + 0) * 16 + lm) * 4 + wm] = ss[0];
      red_l[((wn * 2 + 1) * 16 + lm) * 4 + wm] = ss[1];
    }
  }
  __syncthreads();   // (2) qc_l + red ready

  // qproj (A prefetched) + rms fold + direct global write of qpb
  f32x4 acc2[2][2];
#pragma unroll
  for (int a = 0; a < 2; a++)
#pragma unroll
    for (int n = 0; n < 2; n++) acc2[a][n] = (f32x4){0.f, 0.f, 0.f, 0.f};
#pragma unroll
  for (int kc = 0; kc < 4; kc++) {
#pragma unroll
    for (int ni = 0; ni < 2; ni++) {
      s8b bf = *(const s8b*)&qc_l[((wn * 2 + ni) * 16 + lm) * 136 + kc * 32 + kg * 8];
      acc2[0][ni] = __builtin_amdgcn_mfma_f32_16x16x32_bf16(wq0[kc], bf, acc2[0][ni], 0, 0, 0);
      acc2[1][ni] = __builtin_amdgcn_mfma_f32_16x16x32_bf16(wq1[kc], bf, acc2[1][ni], 0, 0, 0);
    }
  }
#pragma unroll
  for (int ni = 0; ni < 2; ni++) {
    int px = (wn * 2 + ni) * 16 + lm;
    float4 rr = *(const float4*)&red_l[px * 4];
    float rs = rsqrtf((rr.x + rr.y + rr.z + rr.w) * (1.f / 128.f) + EPS_);
    int gpx = (Y0 + (px >> 3)) * 128 + X0 + (px & 7);
#pragma unroll
    for (int mi = 0; mi < 2; mi++) {
      unsigned int lo = (unsigned int)f2bf(((const float*)&qbv[mi])[0] + rs * acc2[mi][ni][0]) |
                        ((unsigned int)f2bf(((const float*)&qbv[mi])[1] + rs * acc2[mi][ni][1]) << 16);
      unsigned int hi = (unsigned int)f2bf(((const float*)&qbv[mi])[2] + rs * acc2[mi][ni][2]) |
                        ((unsigned int)f2bf(((const float*)&qbv[mi])[3] + rs * acc2[mi][ni][3]) << 16);
      uint2 pk = {lo, hi};
      *(uint2*)&qpb[gpx * 128 + wm * 32 + mi * 16 + kg * 4] = pk;
    }
  }
}

// ---------------------------------------------------------------------------
// attn_k: QK^T + masked softmax + PV + out for a 4x8 half-tile (1 cell-row x
// 2 cell-cols). Grid 512 x 256 (4 waves = 1/head; 2 blocks/CU). 4 barriers.
// LDS: q_l [32][136] @0 (8704) | a_l [4][32][68] @8704 (17408)
//      | v_l [128][72] @26112 (18432) | o_l f32 [128][36] @0 (18432, reuse)
//      total 44544B
// ---------------------------------------------------------------------------
__global__ __launch_bounds__(256, 2) void attn_k(
    const unsigned short* __restrict__ qpb, const unsigned short* __restrict__ kpb,
    const unsigned short* __restrict__ vb, float* __restrict__ out) {
  __shared__ __align__(16) char smem[44544];
  unsigned short* q_l = (unsigned short*)smem;
  unsigned short* a_l = (unsigned short*)(smem + 8704);
  unsigned short* v_l = (unsigned short*)(smem + 26112);
  float* o_l = (float*)smem;

  const int tid = threadIdx.x;
  const int CY2 = blockIdx.x >> 4, CX = blockIdx.x & 15;
  const int Y0 = CY2 * 4, X0 = CX * 8;
  const int w = tid >> 6, lane = tid & 63;
  const int lm = lane & 15, kg = lane >> 4;

  const int sy = S_(CY2);
  const int sx0 = S_(2 * CX), sx1 = S_(2 * CX + 1);
  const int kyb = min(sy, 24), kxb = min(sx0, 24);
  const int oy = sy - kyb;
  const int ox0 = sx0 - kxb, ox1 = sx1 - kxb;

  // prefetch K fragments (L2) before staging
  const int h = w;
  s8b bfv[4];
#pragma unroll
  for (int nt = 0; nt < 4; nt++) {
    int n = nt * 16 + lm;
    int ky = n >> 3, kx = n & 7;
    bfv[nt] = *(const s8b*)&kpb[((kyb + ky) * 32 + kxb + kx) * 128 + h * 32 + kg * 8];
  }

  // stage q rows [32 px][128 ch]
  for (int i = tid; i < 512; i += 256) {
    int p = i >> 4, s = i & 15;
    int gpx = (Y0 + (p >> 3)) * 128 + X0 + (p & 7);
    *(s8b*)&q_l[p * 136 + s * 8] = *(const s8b*)&qpb[gpx * 128 + s * 8];
  }
  // stage V window [128 ch][72 key]
  {
    const int kxe = kxb & ~1;
    for (int i = tid; i < 1024; i += 256) {
      int ch = i & 127, ky = i >> 7;
      const unsigned short* src = &vb[ch * 1024 + (kyb + ky) * 32 + kxe];
      s8b a = *(const s8b*)src;
      if (kxb & 1) {
        s8b bsec = *(const s8b*)(src + 8);
        s8b o;
#pragma unroll
        for (int e = 0; e < 7; e++) o[e] = a[e + 1];
        o[7] = bsec[0];
        *(s8b*)&v_l[ch * 72 + ky * 8] = o;
      } else {
        *(s8b*)&v_l[ch * 72 + ky * 8] = a;
      }
    }
  }
  __syncthreads();   // (1) q_l + v_l staged

  // QK^T: wave = head, 32 q-px x 64 keys
  f32x4 lg[2][4];
  {
    s8b af[2];
#pragma unroll
    for (int i = 0; i < 2; i++)
      af[i] = *(const s8b*)&q_l[(i * 16 + lm) * 136 + h * 32 + kg * 8];
#pragma unroll
    for (int i = 0; i < 2; i++)
#pragma unroll
      for (int nt = 0; nt < 4; nt++)
        lg[i][nt] = __builtin_amdgcn_mfma_f32_16x16x32_bf16(
            af[i], bfv[nt], (f32x4){0.f, 0.f, 0.f, 0.f}, 0, 0, 0);
  }

  // masked softmax, store P_h bf16 (a_l separate region -> no barrier needed)
  const int kyA = lm >> 3, kxq = lm & 7;
  const bool kxv0 = (unsigned)(kxq - ox0) < 7u;
  const bool kxv1 = (unsigned)(kxq - ox1) < 7u;
#pragma unroll
  for (int i = 0; i < 2; i++) {
#pragma unroll
    for (int r = 0; r < 4; r++) {
      int q = i * 16 + kg * 4 + r;
      bool kxv = (kg & 1) ? kxv1 : kxv0;    // x-cell = (q>>2)&1 = kg&1
      float l[4];
#pragma unroll
      for (int nt = 0; nt < 4; nt++) {
        int ky = 2 * nt + kyA;
        bool valid = kxv && ((unsigned)(ky - oy) < 7u);
        l[nt] = valid ? lg[i][nt][r] * SCALE_ : -1e30f;
      }
      float mx = fmaxf(fmaxf(l[0], l[1]), fmaxf(l[2], l[3]));
#pragma unroll
      for (int off = 1; off < 16; off <<= 1) mx = fmaxf(mx, __shfl_xor(mx, off, 64));
      float e0 = __expf(l[0] - mx), e1 = __expf(l[1] - mx);
      float e2 = __expf(l[2] - mx), e3 = __expf(l[3] - mx);
      float ss = e0 + e1 + e2 + e3;
#pragma unroll
      for (int off = 1; off < 16; off <<= 1) ss += __shfl_xor(ss, off, 64);
      float inv = 1.f / ss;
      unsigned short* ap = &a_l[(h * 32 + q) * 68];
      ap[lm] = f2bf(e0 * inv);
      ap[16 + lm] = f2bf(e1 * inv);
      ap[32 + lm] = f2bf(e2 * inv);
      ap[48 + lm] = f2bf(e3 * inv);
    }
  }
  __syncthreads();   // (2) a_l ready

  // PV: wave = 32-ch band; O = 0.25 * sum_h P_h . V
  f32x4 oacc[2][2];
#pragma unroll
  for (int a = 0; a < 2; a++)
#pragma unroll
    for (int n = 0; n < 2; n++) oacc[a][n] = (f32x4){0.f, 0.f, 0.f, 0.f};
#pragma unroll
  for (int kc = 0; kc < 2; kc++) {
    s8b bfr[2];
#pragma unroll
    for (int nt2 = 0; nt2 < 2; nt2++)
      bfr[nt2] = *(const s8b*)&v_l[(w * 32 + nt2 * 16 + lm) * 72 + kc * 32 + kg * 8];
#pragma unroll
    for (int hh = 0; hh < 4; hh++) {
#pragma unroll
      for (int mt = 0; mt < 2; mt++) {
        s8b afr = *(const s8b*)&a_l[(hh * 32 + mt * 16 + lm) * 68 + kc * 32 + kg * 8];
#pragma unroll
        for (int nt2 = 0; nt2 < 2; nt2++)
          oacc[mt][nt2] = __builtin_amdgcn_mfma_f32_16x16x32_bf16(afr, bfr[nt2], oacc[mt][nt2], 0, 0, 0);
      }
    }
  }
  __syncthreads();   // (3) a_l reads done; o_l overwrites region0
#pragma unroll
  for (int mt = 0; mt < 2; mt++)
#pragma unroll
    for (int nt2 = 0; nt2 < 2; nt2++)
#pragma unroll
      for (int r = 0; r < 4; r++)
        o_l[(w * 32 + nt2 * 16 + lm) * 36 + mt * 16 + kg * 4 + r] = 0.25f * oacc[mt][nt2][r];
  __syncthreads();   // (4) o_l ready
  for (int i = tid; i < 1024; i += 256) {
    int c = i >> 3, rr = i & 7;
    int qy = rr >> 1, hx = rr & 1;
    float4 v = *(const float4*)&o_l[c * 36 + qy * 8 + hx * 4];
    *(float4*)&out[c * 16384 + (Y0 + qy) * 128 + X0 + hx * 4] = v;
  }
}

// ---------------------------------------------------------------------------
extern "C" void kernel_launch(void* const* d_in, const int* in_sizes, int n_in,
                              void* d_out, int out_size, void* d_ws, size_t ws_size,
                              hipStream_t stream) {
  const float* q_in    = (const float*)d_in[0];
  const float* k_in    = (const float*)d_in[1];
  const float* v_in    = (const float*)d_in[2];
  const float* conv_w  = (const float*)d_in[3];
  const float* normq_w = (const float*)d_in[4];
  const float* normk_w = (const float*)d_in[5];
  const float* qproj_w = (const float*)d_in[6];
  const float* qproj_b = (const float*)d_in[7];
  const float* kproj_w = (const float*)d_in[8];
  const float* kproj_b = (const float*)d_in[9];
  float* out = (float*)d_out;

  char* ws = (char*)d_ws;
  unsigned short* vb  = (unsigned short*)(ws);             // [128][1024] (CHW)
  unsigned short* kpb = (unsigned short*)(ws + 262144);    // [1024][128]
  unsigned short* wb  = (unsigned short*)(ws + 524288);    // [9][4][128][32]
  unsigned short* wnq = (unsigned short*)(ws + 819200);    // [128][128]
  unsigned short* qpb = (unsigned short*)(ws + 851968);    // [16384][128]

  prep_k<<<dim3(60), 512, 0, stream>>>(k_in, v_in, conv_w, normq_w, normk_w,
                                       qproj_w, kproj_w, kproj_b,
                                       vb, kpb, wb, wnq);
  conv_k<<<dim3(256), 512, 0, stream>>>(q_in, wb, wnq, qproj_b, qpb);
  attn_k<<<dim3(512), 256, 0, stream>>>(qpb, kpb, vb, out);
}

// Round 8
// 105.298 us; speedup vs baseline: 1.0875x; 1.0875x over previous
//
#include <hip/hip_runtime.h>

#define EPS_ 1.1920928955078125e-07f
#define SCALE_ 0.17677669529663687f   // 1/sqrt(32)

typedef __attribute__((ext_vector_type(8))) short s8b;     // 8 bf16 (16B)
typedef __attribute__((ext_vector_type(4))) float f32x4;   // MFMA acc

static __device__ __forceinline__ unsigned short f2bf(float f) {
  unsigned int u = __float_as_uint(f);
  unsigned int r = (u + 0x7fffu + ((u >> 16) & 1u)) >> 16;   // RNE
  return (unsigned short)r;
}
static __device__ __forceinline__ float b2fs(short h) {
  return __uint_as_float(((unsigned int)(unsigned short)h) << 16);
}
static __device__ __forceinline__ int S_(int c) {        // NATTEN window start (cell grid)
  return (c < 3) ? 0 : ((c > 28) ? 25 : (c - 3));
}

// ---------------------------------------------------------------------------
// prep (R3's balanced single-round version): grid 193 x 512.
//  [0,128)   q fp32 NCHW -> bf16 NHWC padded qb, 128 px each (2 x 64-px units)
//  [128,144) k-side: rms + kproj MFMA -> kpb [1024][128] (64 px/blk)
//  [144,176) wb pack: 9 consecutive floats/thread, coalesced writes
//  [176,184) v fp32 -> bf16 CHW convert
//  [184,188) wnq = qproj_w * normq pack
//  [188,193) qb halo border zero
// ---------------------------------------------------------------------------
__global__ __launch_bounds__(512) void prep_k(
    const float* __restrict__ q_in, const float* __restrict__ k_in,
    const float* __restrict__ v_in, const float* __restrict__ conv_w,
    const float* __restrict__ normq_w, const float* __restrict__ normk_w,
    const float* __restrict__ qproj_w, const float* __restrict__ kproj_w,
    const float* __restrict__ kbias,
    unsigned short* __restrict__ qb, unsigned short* __restrict__ vb,
    unsigned short* __restrict__ kpb, unsigned short* __restrict__ wb,
    unsigned short* __restrict__ wnq) {
  __shared__ __align__(16) char smem[54528];
  const int b = blockIdx.x, tid = threadIdx.x;
  const int w = tid >> 6, lane = tid & 63;
  const int lm = lane & 15, kg = lane >> 4;
  const int wm = w >> 1, wn = w & 1;

  if (b < 128) {
    unsigned short* t_l = (unsigned short*)smem;   // [64][136]
#pragma unroll
    for (int u = 0; u < 2; u++) {
      const int px0 = b * 128 + u * 64;
      for (int i = tid; i < 2048; i += 512) {
        int c = i >> 4, f = i & 15;
        float4 v = *(const float4*)&q_in[c * 16384 + px0 + f * 4];
        t_l[(f * 4 + 0) * 136 + c] = f2bf(v.x);
        t_l[(f * 4 + 1) * 136 + c] = f2bf(v.y);
        t_l[(f * 4 + 2) * 136 + c] = f2bf(v.z);
        t_l[(f * 4 + 3) * 136 + c] = f2bf(v.w);
      }
      __syncthreads();
      for (int i = tid; i < 1024; i += 512) {
        int p = i >> 4, s = i & 15;
        int px = px0 + p;
        int opx = px + 2 * (px >> 7) + 131;   // (y+1)*130 + (x+1)
        *(s8b*)&qb[opx * 128 + s * 8] = *(const s8b*)&t_l[p * 136 + s * 8];
      }
      __syncthreads();
    }
  } else if (b < 144) {
    unsigned short* x_l = (unsigned short*)smem;            // [64][136]
    unsigned short* wnk_l = (unsigned short*)(smem + 17408);// [128][136]
    float* red_l = (float*)(smem + 52224);                  // [512]
    float* rs_l  = (float*)(smem + 54272);                  // [64]
    const int px0 = (b - 128) * 64;
    for (int i = tid; i < 2048; i += 512) {   // stage k transposed bf16
      int c = i >> 4, f = i & 15;
      float4 v = *(const float4*)&k_in[c * 1024 + px0 + f * 4];
      x_l[(f * 4 + 0) * 136 + c] = f2bf(v.x);
      x_l[(f * 4 + 1) * 136 + c] = f2bf(v.y);
      x_l[(f * 4 + 2) * 136 + c] = f2bf(v.z);
      x_l[(f * 4 + 3) * 136 + c] = f2bf(v.w);
    }
    for (int i = tid; i < 16384; i += 512) {  // wnk = kproj_w * normk
      int o = i >> 7, c = i & 127;
      wnk_l[o * 136 + c] = f2bf(kproj_w[i] * normk_w[c]);
    }
    __syncthreads();
    {
      int px = tid >> 3, t8 = tid & 7;
      float ssum = 0.f;
#pragma unroll
      for (int j = 0; j < 2; j++) {
        s8b v = *(const s8b*)&x_l[px * 136 + t8 * 16 + j * 8];
#pragma unroll
        for (int e = 0; e < 8; e++) { float f = b2fs(v[e]); ssum += f * f; }
      }
      red_l[px * 8 + t8] = ssum;
    }
    __syncthreads();
    if (tid < 64) {
      float4 r0 = *(const float4*)&red_l[tid * 8];
      float4 r1 = *(const float4*)&red_l[tid * 8 + 4];
      rs_l[tid] = rsqrtf((r0.x + r0.y + r0.z + r0.w + r1.x + r1.y + r1.z + r1.w) *
                             (1.f / 128.f) + EPS_);
    }
    __syncthreads();
    f32x4 acc[2][2];
#pragma unroll
    for (int a = 0; a < 2; a++)
#pragma unroll
      for (int n = 0; n < 2; n++) acc[a][n] = (f32x4){0.f, 0.f, 0.f, 0.f};
#pragma unroll
    for (int kc = 0; kc < 4; kc++) {
      s8b a0 = *(const s8b*)&wnk_l[(wm * 32 + lm) * 136 + kc * 32 + kg * 8];
      s8b a1 = *(const s8b*)&wnk_l[(wm * 32 + 16 + lm) * 136 + kc * 32 + kg * 8];
#pragma unroll
      for (int ni = 0; ni < 2; ni++) {
        s8b bf = *(const s8b*)&x_l[((wn * 2 + ni) * 16 + lm) * 136 + kc * 32 + kg * 8];
        acc[0][ni] = __builtin_amdgcn_mfma_f32_16x16x32_bf16(a0, bf, acc[0][ni], 0, 0, 0);
        acc[1][ni] = __builtin_amdgcn_mfma_f32_16x16x32_bf16(a1, bf, acc[1][ni], 0, 0, 0);
      }
    }
    __syncthreads();
#pragma unroll
    for (int mi = 0; mi < 2; mi++)
#pragma unroll
      for (int ni = 0; ni < 2; ni++)
#pragma unroll
        for (int r = 0; r < 4; r++) {
          int px = (wn * 2 + ni) * 16 + lm, c = wm * 32 + mi * 16 + kg * 4 + r;
          x_l[px * 136 + c] = f2bf(kbias[c] + rs_l[px] * acc[mi][ni][r]);
        }
    __syncthreads();
    for (int i = tid; i < 1024; i += 512) {
      int px = i >> 4, s = i & 15;
      *(s8b*)&kpb[(px0 + px) * 128 + s * 8] = *(const s8b*)&x_l[px * 136 + s * 8];
    }
  } else if (b < 176) {
    int g = (b - 144) * 512 + tid;            // [0,16384)
    int i32 = g & 31, oc = (g >> 5) & 127, kc = g >> 12;
    const float* src = conv_w + oc * 1152 + (kc * 32 + i32) * 9;
#pragma unroll
    for (int t = 0; t < 9; t++)
      wb[t * 16384 + g] = f2bf(src[t]);
  } else if (b < 184) {
#pragma unroll
    for (int it = 0; it < 4; it++) {
      int ch8 = (b - 176) * 2048 + it * 512 + tid;   // [0,16384) chunks of 8
      const float4 v0 = *(const float4*)&v_in[ch8 * 8];
      const float4 v1 = *(const float4*)&v_in[ch8 * 8 + 4];
      s8b o;
      o[0] = (short)f2bf(v0.x); o[1] = (short)f2bf(v0.y);
      o[2] = (short)f2bf(v0.z); o[3] = (short)f2bf(v0.w);
      o[4] = (short)f2bf(v1.x); o[5] = (short)f2bf(v1.y);
      o[6] = (short)f2bf(v1.z); o[7] = (short)f2bf(v1.w);
      *(s8b*)&vb[ch8 * 8] = o;
    }
  } else if (b < 188) {
    int base = ((b - 184) * 512 + tid) * 8;   // [0,16384)
    const float4 v0 = *(const float4*)&qproj_w[base];
    const float4 v1 = *(const float4*)&qproj_w[base + 4];
    int c = base & 127;
    s8b o;
    o[0] = (short)f2bf(v0.x * normq_w[c + 0]); o[1] = (short)f2bf(v0.y * normq_w[c + 1]);
    o[2] = (short)f2bf(v0.z * normq_w[c + 2]); o[3] = (short)f2bf(v0.w * normq_w[c + 3]);
    o[4] = (short)f2bf(v1.x * normq_w[c + 4]); o[5] = (short)f2bf(v1.y * normq_w[c + 5]);
    o[6] = (short)f2bf(v1.z * normq_w[c + 6]); o[7] = (short)f2bf(v1.w * normq_w[c + 7]);
    *(s8b*)&wnq[base] = o;
  } else {
    int gid = (b - 188) * 512 + tid;          // [0,2560)
    s8b z = {0, 0, 0, 0, 0, 0, 0, 0};
    if (gid < 2080) {
      *(s8b*)&qb[gid * 8] = z;
      *(s8b*)&qb[129 * 130 * 128 + gid * 8] = z;
    }
    if (gid < 2048) {
      int r = (gid >> 4) + 1, s = gid & 15;
      *(s8b*)&qb[(r * 130) * 128 + s * 8] = z;
      *(s8b*)&qb[(r * 130 + 129) * 128 + s * 8] = z;
    }
  }
}

// ---------------------------------------------------------------------------
// fused (R1 structure + R6 refinements, race-fixed): grid 256 x 512.
// qb bf16 halo staging (vector b128, no conflicts); prefetched kpb/wnq/qbias
// fragments; in-register RMS from conv f32 accumulators; rs folded into
// qproj epilogue; QK intra-wave after in-place qc_l update. 8 barriers.
// LDS: region0 @0 (34816B): in_l [10][12][136] -> qc_l [64][136]
//      -> a_l [4][64][68] -> o_l [128][68] f32
//      region1 @34816 (18432B): v_l [128][72]
//      red @53248 (1024B)  total 54272B
// ---------------------------------------------------------------------------
__global__ __launch_bounds__(512, 2) void fused_k(
    const unsigned short* __restrict__ qb, const unsigned short* __restrict__ wb,
    const unsigned short* __restrict__ wnq, const float* __restrict__ qbias,
    const unsigned short* __restrict__ kpb, const unsigned short* __restrict__ vb,
    float* __restrict__ out) {
  __shared__ __align__(16) char smem[54272];
  unsigned short* in_l = (unsigned short*)smem;
  unsigned short* qc_l = (unsigned short*)smem;
  unsigned short* a_l  = (unsigned short*)smem;
  float* o_l = (float*)smem;
  unsigned short* v_l = (unsigned short*)(smem + 34816);
  float* red_l = (float*)(smem + 53248);     // [64][4]

  const int tid = threadIdx.x;
  const int CY = blockIdx.x >> 4, CX = blockIdx.x & 15;
  const int Y0 = CY * 8, X0 = CX * 8;
  const int w = tid >> 6, lane = tid & 63;
  const int lm = lane & 15, kg = lane >> 4;
  const int wm = w >> 1, wn = w & 1;        // conv/qproj: 4 M-bands x 2 N-halves

  const int sy0 = S_(2 * CY), sy1 = S_(2 * CY + 1);
  const int sx0 = S_(2 * CX), sx1 = S_(2 * CX + 1);
  const int kyb = min(sy0, 24), kxb = min(sx0, 24);
  const int oy0 = sy0 - kyb, oy1 = sy1 - kyb;
  const int ox0 = sx0 - kxb, ox1 = sx1 - kxb;

  // ---- prefetch later-phase global operands (L2) into registers ----
  const int h = w >> 1, qh = w & 1;         // QK role
  s8b bfv[4];                                // kpb B-frags for QK
#pragma unroll
  for (int nt = 0; nt < 4; nt++) {
    int n = nt * 16 + lm;
    int ky = n >> 3, kx = n & 7;
    bfv[nt] = *(const s8b*)&kpb[((kyb + ky) * 32 + kxb + kx) * 128 + h * 32 + kg * 8];
  }
  s8b wq0[4], wq1[4];                        // wnq A-frags for qproj
#pragma unroll
  for (int kc = 0; kc < 4; kc++) {
    wq0[kc] = *(const s8b*)&wnq[(wm * 32 + lm) * 128 + kc * 32 + kg * 8];
    wq1[kc] = *(const s8b*)&wnq[(wm * 32 + 16 + lm) * 128 + kc * 32 + kg * 8];
  }
  float4 qbv[2];
  qbv[0] = *(const float4*)&qbias[wm * 32 + kg * 4];
  qbv[1] = *(const float4*)&qbias[wm * 32 + 16 + kg * 4];

  // ---- stage conv halo [10][12(pad)][136] from packed qb (vector b128) ----
  for (int i = tid; i < 1600; i += 512) {
    int s = i & 15, r = i >> 4;
    int ry = r / 10, rx = r - ry * 10;
    *(s8b*)&in_l[(ry * 12 + rx) * 136 + s * 8] =
        *(const s8b*)&qb[((Y0 + ry) * 130 + X0 + rx) * 128 + s * 8];
  }
  // ---- stage V window: vb [128ch][1024px] -> v_l [128ch][72key] via b128 ----
  {
    const int kxe = kxb & ~1;               // 4B-aligned dwordx4 base
    for (int i = tid; i < 1024; i += 512) {
      int ch = i & 127, ky = i >> 7;
      const unsigned short* src = &vb[ch * 1024 + (kyb + ky) * 32 + kxe];
      s8b a = *(const s8b*)src;
      if (kxb & 1) {                         // block-uniform branch
        s8b bsec = *(const s8b*)(src + 8);
        s8b o;
#pragma unroll
        for (int e = 0; e < 7; e++) o[e] = a[e + 1];
        o[7] = bsec[0];
        *(s8b*)&v_l[ch * 72 + ky * 8] = o;
      } else {
        *(s8b*)&v_l[ch * 72 + ky * 8] = a;
      }
    }
  }
  __syncthreads();   // (1) halo + V staged

  // ---- conv implicit GEMM, weight stream double-buffered in registers ----
  f32x4 acc[2][2];
#pragma unroll
  for (int a = 0; a < 2; a++)
#pragma unroll
    for (int n = 0; n < 2; n++) acc[a][n] = (f32x4){0.f, 0.f, 0.f, 0.f};
  {
    s8b wa0 = *(const s8b*)&wb[(wm * 32 + lm) * 32 + kg * 8];
    s8b wa1 = *(const s8b*)&wb[(wm * 32 + 16 + lm) * 32 + kg * 8];
#pragma unroll
    for (int idx = 0; idx < 36; idx++) {
      s8b na0 = wa0, na1 = wa1;
      if (idx < 35) {
        const unsigned short* wp = wb + (idx + 1) * 4096;
        na0 = *(const s8b*)&wp[(wm * 32 + lm) * 32 + kg * 8];
        na1 = *(const s8b*)&wp[(wm * 32 + 16 + lm) * 32 + kg * 8];
      }
      const int t = idx >> 2, kc = idx & 3;
      const int dy = t / 3, dx = t - (t / 3) * 3;
#pragma unroll
      for (int ni = 0; ni < 2; ni++) {
        int nt = wn * 2 + ni;
        int qy = 2 * nt + (lm >> 3), qx = lm & 7;
        s8b bf = *(const s8b*)&in_l[((qy + dy) * 12 + qx + dx) * 136 + kc * 32 + kg * 8];
        acc[0][ni] = __builtin_amdgcn_mfma_f32_16x16x32_bf16(wa0, bf, acc[0][ni], 0, 0, 0);
        acc[1][ni] = __builtin_amdgcn_mfma_f32_16x16x32_bf16(wa1, bf, acc[1][ni], 0, 0, 0);
      }
      wa0 = na0; wa1 = na1;
    }
  }
  __syncthreads();   // (2) all in_l reads done (qc_l aliases in_l — race fix)

  // epilogue: write raw conv bf16 + in-register rms partials
  {
    float ss[2] = {0.f, 0.f};
#pragma unroll
    for (int mi = 0; mi < 2; mi++)
#pragma unroll
      for (int ni = 0; ni < 2; ni++)
#pragma unroll
        for (int r = 0; r < 4; r++) {
          float v = acc[mi][ni][r];
          ss[ni] += v * v;
          int px = (wn * 2 + ni) * 16 + lm, c = wm * 32 + mi * 16 + kg * 4 + r;
          qc_l[px * 136 + c] = f2bf(v);
        }
#pragma unroll
    for (int ni = 0; ni < 2; ni++) {
      ss[ni] += __shfl_xor(ss[ni], 16, 64);
      ss[ni] += __shfl_xor(ss[ni], 32, 64);
    }
    if (kg == 0) {
      red_l[((wn * 2 + 0) * 16 + lm) * 4 + wm] = ss[0];
      red_l[((wn * 2 + 1) * 16 + lm) * 4 + wm] = ss[1];
    }
  }
  __syncthreads();   // (3) qc_l (raw conv) + red ready

  // ---- qproj: A prefetched, B from qc_l ----
  f32x4 acc2[2][2];
#pragma unroll
  for (int a = 0; a < 2; a++)
#pragma unroll
    for (int n = 0; n < 2; n++) acc2[a][n] = (f32x4){0.f, 0.f, 0.f, 0.f};
#pragma unroll
  for (int kc = 0; kc < 4; kc++) {
#pragma unroll
    for (int ni = 0; ni < 2; ni++) {
      s8b bf = *(const s8b*)&qc_l[((wn * 2 + ni) * 16 + lm) * 136 + kc * 32 + kg * 8];
      acc2[0][ni] = __builtin_amdgcn_mfma_f32_16x16x32_bf16(wq0[kc], bf, acc2[0][ni], 0, 0, 0);
      acc2[1][ni] = __builtin_amdgcn_mfma_f32_16x16x32_bf16(wq1[kc], bf, acc2[1][ni], 0, 0, 0);
    }
  }
  __syncthreads();   // (4) qproj reads of qc_l done; in-place overwrite ok
#pragma unroll
  for (int ni = 0; ni < 2; ni++) {
    int px = (wn * 2 + ni) * 16 + lm;
    float4 rr = *(const float4*)&red_l[px * 4];
    float rs = rsqrtf((rr.x + rr.y + rr.z + rr.w) * (1.f / 128.f) + EPS_);
#pragma unroll
    for (int mi = 0; mi < 2; mi++)
#pragma unroll
      for (int r = 0; r < 4; r++) {
        int c = wm * 32 + mi * 16 + kg * 4 + r;
        qc_l[px * 136 + c] = f2bf(((const float*)&qbv[mi])[r] + rs * acc2[mi][ni][r]);
      }
  }

  // ---- QK^T: intra-wave (wave 2h+qh wrote exactly the rows/cols it reads) ----
  f32x4 lg[2][4];
  {
    s8b af[2];
#pragma unroll
    for (int i = 0; i < 2; i++)
      af[i] = *(const s8b*)&qc_l[((qh * 2 + i) * 16 + lm) * 136 + h * 32 + kg * 8];
#pragma unroll
    for (int i = 0; i < 2; i++)
#pragma unroll
      for (int nt = 0; nt < 4; nt++)
        lg[i][nt] = __builtin_amdgcn_mfma_f32_16x16x32_bf16(
            af[i], bfv[nt], (f32x4){0.f, 0.f, 0.f, 0.f}, 0, 0, 0);
  }
  __syncthreads();   // (5) qc_l reads done; a_l overwrites region0

  // ---- masked softmax (per head), store P_h bf16; 8 rows per wave ----
  const int kyA = lm >> 3, kxq = lm & 7;
  const bool kxv0 = (unsigned)(kxq - ox0) < 7u;
  const bool kxv1 = (unsigned)(kxq - ox1) < 7u;
#pragma unroll
  for (int i = 0; i < 2; i++) {
    const int mt = qh * 2 + i;
#pragma unroll
    for (int r = 0; r < 4; r++) {
      int j = mt * 16 + kg * 4 + r;
      int oy = ((j >> 5) & 1) ? oy1 : oy0;
      bool kxv = ((j >> 2) & 1) ? kxv1 : kxv0;
      float l[4];
#pragma unroll
      for (int nt = 0; nt < 4; nt++) {
        int ky = 2 * nt + kyA;
        bool valid = kxv && ((unsigned)(ky - oy) < 7u);
        l[nt] = valid ? lg[i][nt][r] * SCALE_ : -1e30f;
      }
      float mx = fmaxf(fmaxf(l[0], l[1]), fmaxf(l[2], l[3]));
#pragma unroll
      for (int off = 1; off < 16; off <<= 1) mx = fmaxf(mx, __shfl_xor(mx, off, 64));
      float e0 = __expf(l[0] - mx), e1 = __expf(l[1] - mx);
      float e2 = __expf(l[2] - mx), e3 = __expf(l[3] - mx);
      float ss = e0 + e1 + e2 + e3;
#pragma unroll
      for (int off = 1; off < 16; off <<= 1) ss += __shfl_xor(ss, off, 64);
      float inv = 1.f / ss;
      unsigned short* ap = &a_l[(h * 64 + j) * 68];
      ap[lm] = f2bf(e0 * inv);
      ap[16 + lm] = f2bf(e1 * inv);
      ap[32 + lm] = f2bf(e2 * inv);
      ap[48 + lm] = f2bf(e3 * inv);
    }
  }
  __syncthreads();   // (6) a_l ready

  // ---- PV: O = 0.25 * sum_h P_h · V ; wave = 32px x 32ch ----
  const int ph = w & 1, cb = w >> 1;
  f32x4 oacc[2][2];
#pragma unroll
  for (int a = 0; a < 2; a++)
#pragma unroll
    for (int n = 0; n < 2; n++) oacc[a][n] = (f32x4){0.f, 0.f, 0.f, 0.f};
#pragma unroll
  for (int kc = 0; kc < 2; kc++) {
    s8b bfr[2];
#pragma unroll
    for (int nt2 = 0; nt2 < 2; nt2++)
      bfr[nt2] = *(const s8b*)&v_l[(cb * 32 + nt2 * 16 + lm) * 72 + kc * 32 + kg * 8];
#pragma unroll
    for (int hh = 0; hh < 4; hh++) {
#pragma unroll
      for (int mi = 0; mi < 2; mi++) {
        s8b afr = *(const s8b*)&a_l[(hh * 64 + (ph * 2 + mi) * 16 + lm) * 68 + kc * 32 + kg * 8];
#pragma unroll
        for (int nt2 = 0; nt2 < 2; nt2++)
          oacc[mi][nt2] = __builtin_amdgcn_mfma_f32_16x16x32_bf16(afr, bfr[nt2], oacc[mi][nt2], 0, 0, 0);
      }
    }
  }
  __syncthreads();   // (7) a_l reads done before o_l overwrite
#pragma unroll
  for (int mi = 0; mi < 2; mi++)
#pragma unroll
    for (int nt2 = 0; nt2 < 2; nt2++)
#pragma unroll
      for (int r = 0; r < 4; r++)
        o_l[(cb * 32 + nt2 * 16 + lm) * 68 + (ph * 2 + mi) * 16 + kg * 4 + r] =
            0.25f * oacc[mi][nt2][r];
  __syncthreads();   // (8) o_l ready
  for (int i = tid; i < 2048; i += 512) {
    int c = i >> 4, rr = i & 15;
    int qy = rr >> 1, hx = rr & 1;
    float4 v = *(const float4*)&o_l[c * 68 + qy * 8 + hx * 4];
    *(float4*)&out[c * 16384 + (Y0 + qy) * 128 + X0 + hx * 4] = v;
  }
}

// ---------------------------------------------------------------------------
extern "C" void kernel_launch(void* const* d_in, const int* in_sizes, int n_in,
                              void* d_out, int out_size, void* d_ws, size_t ws_size,
                              hipStream_t stream) {
  const float* q_in    = (const float*)d_in[0];
  const float* k_in    = (const float*)d_in[1];
  const float* v_in    = (const float*)d_in[2];
  const float* conv_w  = (const float*)d_in[3];
  const float* normq_w = (const float*)d_in[4];
  const float* normk_w = (const float*)d_in[5];
  const float* qproj_w = (const float*)d_in[6];
  const float* qproj_b = (const float*)d_in[7];
  const float* kproj_w = (const float*)d_in[8];
  const float* kproj_b = (const float*)d_in[9];
  float* out = (float*)d_out;

  char* ws = (char*)d_ws;
  unsigned short* qb  = (unsigned short*)(ws);             // [130][130][128]
  unsigned short* vb  = (unsigned short*)(ws + 4326400);   // [128][1024] (CHW)
  unsigned short* kpb = (unsigned short*)(ws + 4588544);   // [1024][128]
  unsigned short* wb  = (unsigned short*)(ws + 4850688);   // [9][4][128][32]
  unsigned short* wnq = (unsigned short*)(ws + 5145600);   // [128][128]

  prep_k<<<dim3(193), 512, 0, stream>>>(q_in, k_in, v_in, conv_w, normq_w, normk_w,
                                        qproj_w, kproj_w, kproj_b,
                                        qb, vb, kpb, wb, wnq);
  fused_k<<<dim3(256), 512, 0, stream>>>(qb, wb, wnq, qproj_b, kpb, vb, out);
}